// Round 5
// baseline (254.114 us; speedup 1.0000x reference)
//
#include <hip/hip_runtime.h>
#include <hip/hip_bf16.h>

#define B_ 2
#define S_ 1024
#define F_ 1024
#define H_ 8
#define D_ 64
#define R_ 2
#define BH (B_*H_)
#define NC 32
#define CL (S_/NC)   // 32

// combined projection layout: [M, NPROJ] fp32
#define QOFF 0
#define KOFF 512
#define VOFF 1536
#define BOFF 2560
#define NPROJ 2624   // 41 * 64

typedef __bf16 bf16x8 __attribute__((ext_vector_type(8)));
typedef unsigned short ushort8 __attribute__((ext_vector_type(8)));
typedef float f32x4 __attribute__((ext_vector_type(4)));

__device__ __forceinline__ unsigned short f2bf(float f) {
    unsigned u = __builtin_bit_cast(unsigned, f);
    unsigned r = u + 0x7FFFu + ((u >> 16) & 1u);
    return (unsigned short)(r >> 16);
}

__device__ __forceinline__ void gload_lds16(const void* g, void* l) {
    __builtin_amdgcn_global_load_lds(
        (const __attribute__((address_space(1))) void*)g,
        (__attribute__((address_space(3))) void*)l, 16, 0, 0);
}

// ------------------------------------------------------------------
// Mask format sniffer + normalize to float 0/1.
// ------------------------------------------------------------------
__global__ void k_mask_prep(const void* __restrict__ mraw, float* __restrict__ maskf, int n) {
    __shared__ int fmt; // 0=int32, 1=byte, 2=float32
    int t = threadIdx.x;
    if (t == 0) fmt = 0;
    __syncthreads();
    const unsigned int* u32 = (const unsigned int*)mraw;
    for (int g = t; g < n / 4; g += blockDim.x) {
        unsigned int v = u32[g];
        if (v == 0x3F800000u) atomicMax(&fmt, 2);
        else if (v != 0u && v != 1u) atomicMax(&fmt, 1);
    }
    __syncthreads();
    int f = fmt;
    const unsigned char* u8 = (const unsigned char*)mraw;
    const float* f32 = (const float*)mraw;
    for (int i = t; i < n; i += blockDim.x) {
        float mv;
        if (f == 1)      mv = u8[i] ? 1.f : 0.f;
        else if (f == 2) mv = (f32[i] != 0.f) ? 1.f : 0.f;
        else             mv = (u32[i] != 0u) ? 1.f : 0.f;
        maskf[i] = mv;
    }
}

// ------------------------------------------------------------------
// fp32 -> bf16 elementwise (n % 4 == 0)
// ------------------------------------------------------------------
__global__ void k_f32_to_bf16(const float* __restrict__ s, unsigned short* __restrict__ d, int n) {
    int i = (blockIdx.x * blockDim.x + threadIdx.x) * 4;
    if (i < n) {
        float4 v = *(const float4*)&s[i];
        d[i + 0] = f2bf(v.x); d[i + 1] = f2bf(v.y);
        d[i + 2] = f2bf(v.z); d[i + 3] = f2bf(v.w);
    }
}

// ------------------------------------------------------------------
// Transpose [K,N] f32 -> [N,K] bf16. 32x32 tiles, 256 threads.
// ------------------------------------------------------------------
__global__ __launch_bounds__(256) void k_transpose_to_bf16(
    const float* __restrict__ src, unsigned short* __restrict__ dst, int K, int N)
{
    __shared__ float tile[32][33];
    int bx = blockIdx.x, by = blockIdx.y;
    int tx = threadIdx.x & 31, ty = threadIdx.x >> 5;
#pragma unroll
    for (int i = 0; i < 32; i += 8)
        tile[ty + i][tx] = src[(size_t)(by * 32 + ty + i) * N + bx * 32 + tx];
    __syncthreads();
#pragma unroll
    for (int i = 0; i < 32; i += 8)
        dst[(size_t)(bx * 32 + ty + i) * K + by * 32 + tx] = f2bf(tile[tx][ty + i]);
}

// ------------------------------------------------------------------
// Wb [1024,16] f32 -> rows BOFF..BOFF+63 of wt as [64,1024] bf16,
// rows 16..63 zero.
// ------------------------------------------------------------------
__global__ void k_wb_pad(const float* __restrict__ Wb, unsigned short* __restrict__ dst) {
    int row = blockIdx.x;          // 0..63
    int c0 = threadIdx.x * 4;      // 0..1020
#pragma unroll
    for (int c = c0; c < c0 + 4; ++c)
        dst[(size_t)row * 1024 + c] = (row < 16) ? f2bf(Wb[(size_t)c * 16 + row]) : (unsigned short)0;
}

// ------------------------------------------------------------------
// bf16 MFMA GEMM: C[M,N] = A[M,K] @ B[K,N] (+bias). Tile 128x64, BK=64.
// ------------------------------------------------------------------
__global__ __launch_bounds__(256) void k_gemm_bf16(
    const unsigned short* __restrict__ A, const unsigned short* __restrict__ Bt,
    const float* __restrict__ bias, float* __restrict__ C,
    int M, int N, int K)
{
    constexpr int BM = 128, BN = 64, BK = 64;
    __shared__ unsigned short sA[BM * BK];
    __shared__ unsigned short sB[BN * BK];
    int t = threadIdx.x;
    int w = t >> 6, l = t & 63;
    int rowb = blockIdx.y * BM, colb = blockIdx.x * BN;
    int wr = w >> 1, wc = w & 1;
    int fr = l & 15, kgrp = l >> 4;

    f32x4 acc[4][2];
#pragma unroll
    for (int m = 0; m < 4; ++m)
#pragma unroll
        for (int n = 0; n < 2; ++n) acc[m][n] = (f32x4){0.f, 0.f, 0.f, 0.f};

    int lrow_off = l >> 3;
    int kg_phys = l & 7;

    for (int k0 = 0; k0 < K; k0 += BK) {
        __syncthreads();
#pragma unroll
        for (int is = 0; is < 4; ++is) {
            int r0 = (w * 4 + is) * 8;
            int row = r0 + lrow_off;
            int kg_log = kg_phys ^ (row & 7);
            gload_lds16(A + (size_t)(rowb + row) * K + k0 + kg_log * 8, &sA[r0 * BK]);
        }
#pragma unroll
        for (int is = 0; is < 2; ++is) {
            int r0 = (w * 2 + is) * 8;
            int row = r0 + lrow_off;
            int kg_log = kg_phys ^ (row & 7);
            gload_lds16(Bt + (size_t)(colb + row) * K + k0 + kg_log * 8, &sB[r0 * BK]);
        }
        asm volatile("s_waitcnt vmcnt(0)" ::: "memory");
        __syncthreads();

#pragma unroll
        for (int kk = 0; kk < BK; kk += 32) {
            int kg = (kk >> 3) + kgrp;
            bf16x8 af[4], bfv[2];
#pragma unroll
            for (int m = 0; m < 4; ++m) {
                int row = wr * 64 + m * 16 + fr;
                ushort8 raw = *(const ushort8*)&sA[row * BK + (kg ^ (row & 7)) * 8];
                af[m] = __builtin_bit_cast(bf16x8, raw);
            }
#pragma unroll
            for (int n = 0; n < 2; ++n) {
                int row = wc * 32 + n * 16 + fr;
                ushort8 raw = *(const ushort8*)&sB[row * BK + (kg ^ (row & 7)) * 8];
                bfv[n] = __builtin_bit_cast(bf16x8, raw);
            }
#pragma unroll
            for (int m = 0; m < 4; ++m)
#pragma unroll
                for (int n = 0; n < 2; ++n)
                    acc[m][n] = __builtin_amdgcn_mfma_f32_16x16x32_bf16(af[m], bfv[n], acc[m][n], 0, 0, 0);
        }
    }

#pragma unroll
    for (int m = 0; m < 4; ++m)
#pragma unroll
        for (int n = 0; n < 2; ++n) {
            int grow0 = rowb + wr * 64 + m * 16 + kgrp * 4;
            int gcol  = colb + wc * 32 + n * 16 + fr;
            float bv = bias ? bias[gcol] : 0.f;
#pragma unroll
            for (int r = 0; r < 4; ++r)
                C[(size_t)(grow0 + r) * N + gcol] = acc[m][n][r] + bv;
        }
}

// ------------------------------------------------------------------
// silu then L2-normalize per group of 64 with strided row layout.
// ------------------------------------------------------------------
__global__ void k_silu_norm(float* __restrict__ buf, int ngroups,
                            int gshift, int gmask, int rowstride, int coloff) {
    int w = threadIdx.x >> 6;
    int l = threadIdx.x & 63;
    int g = blockIdx.x * 4 + w;
    if (g >= ngroups) return;
    size_t idx = (size_t)(g >> gshift) * rowstride + coloff + ((g & gmask) << 6) + l;
    float x = buf[idx];
    float s = x / (1.f + expf(-x));
    float ss = s * s;
#pragma unroll
    for (int m = 1; m < 64; m <<= 1) ss += __shfl_xor(ss, m);
    float nrm = sqrtf(ss) + 1e-6f;
    buf[idx] = s / nrm;
}

// ------------------------------------------------------------------
// Phase 1: per (bh, chunk) transfer operators (A_c, B_c).
// Lane-per-row: wave 0 carries the A-state, wave 1 the B-state; each
// lane owns one full state row in 64 VGPRs. No shuffles; k broadcast
// from LDS. Mask is a rare wave-uniform register-zero.
// ------------------------------------------------------------------
__global__ __launch_bounds__(128) void k_chunk_transfer(
    const float* __restrict__ proj, const float* __restrict__ maskf,
    float* __restrict__ Ac, float* __restrict__ Bc)
{
    int c = blockIdx.x;
    int bh = blockIdx.y;
    int b = bh >> 3, h = bh & 7;
    int t = threadIdx.x;
    int w = t >> 6, lane = t & 63;
    __shared__ float sK[CL][128];
    __shared__ float sV[CL][128];
    __shared__ float4 sScal[CL];   // {b0, b1, maskscale, pad}

    size_t tokbase = (size_t)(b * S_ + c * CL);
#pragma unroll
    for (int it = 0; it < (CL * 32) / 128; ++it) {
        int f = it * 128 + t;
        int tok = f >> 5, wi = f & 31;
        *(float4*)&sK[tok][wi * 4] = *(const float4*)&proj[(tokbase + tok) * NPROJ + KOFF + h * 128 + wi * 4];
        *(float4*)&sV[tok][wi * 4] = *(const float4*)&proj[(tokbase + tok) * NPROJ + VOFF + h * 128 + wi * 4];
    }
    if (t < CL) {
        float r0 = proj[(tokbase + t) * NPROJ + BOFF + h * 2 + 0];
        float r1 = proj[(tokbase + t) * NPROJ + BOFF + h * 2 + 1];
        float ms = 1.f - maskf[tokbase + t];
        sScal[t] = make_float4(1.f / (1.f + expf(-r0)), 1.f / (1.f + expf(-r1)), ms, 0.f);
    }
    __syncthreads();

    float St[64];
#pragma unroll
    for (int j = 0; j < 64; ++j) St[j] = (w == 0 && j == lane) ? 1.f : 0.f;

    for (int sl = 0; sl < CL; ++sl) {
        float4 sc = sScal[sl];
        if (sc.z == 0.f) {           // masked token: state resets (wave-uniform, ~5%)
#pragma unroll
            for (int j = 0; j < 64; ++j) St[j] = 0.f;
        }
#pragma unroll
        for (int r = 0; r < 2; ++r) {
            float br = (r == 0) ? sc.x : sc.y;
            float vi = sV[sl][r * 64 + lane];
            float4 kk[16];
#pragma unroll
            for (int j = 0; j < 16; ++j) kk[j] = *(const float4*)&sK[sl][r * 64 + j * 4];
            float u0 = 0.f, u1 = 0.f, u2 = 0.f, u3 = 0.f;
#pragma unroll
            for (int j = 0; j < 16; ++j) {
                u0 = fmaf(St[j * 4 + 0], kk[j].x, u0);
                u1 = fmaf(St[j * 4 + 1], kk[j].y, u1);
                u2 = fmaf(St[j * 4 + 2], kk[j].z, u2);
                u3 = fmaf(St[j * 4 + 3], kk[j].w, u3);
            }
            float u = (u0 + u1) + (u2 + u3);
            float coef = (w == 0) ? (-br * u) : (br * (vi - u));
#pragma unroll
            for (int j = 0; j < 16; ++j) {
                St[j * 4 + 0] = fmaf(coef, kk[j].x, St[j * 4 + 0]);
                St[j * 4 + 1] = fmaf(coef, kk[j].y, St[j * 4 + 1]);
                St[j * 4 + 2] = fmaf(coef, kk[j].z, St[j * 4 + 2]);
                St[j * 4 + 3] = fmaf(coef, kk[j].w, St[j * 4 + 3]);
            }
        }
    }
    float* dst = (w == 0 ? Ac : Bc) + ((size_t)bh * NC + c) * 4096 + (size_t)lane * 64;
#pragma unroll
    for (int j = 0; j < 16; ++j)
        *(float4*)&dst[j * 4] = make_float4(St[j * 4], St[j * 4 + 1], St[j * 4 + 2], St[j * 4 + 3]);
}

// ------------------------------------------------------------------
// Phase 2: sequential chunk combine, split by state ROWS.
// 64 blocks = 16 bh x 4 row-groups of 16 rows. S0 aliases Bc.
// Register double-buffer prefetch of the next A chunk.
// ------------------------------------------------------------------
__global__ __launch_bounds__(256) void k_combine(
    const float* __restrict__ Ac, const float* Bc,
    const float* __restrict__ carry, float* S0,
    float* __restrict__ carry_out)
{
    int blk = blockIdx.x;
    int bh = blk >> 2, rg = blk & 3;
    int t = threadIdx.x;
    int i = t >> 4;
    int j0 = (t & 15) * 4;
    int gi = rg * 16 + i;
    __shared__ float sA[64 * 64];
    __shared__ float sS[16 * 64];

    *(float4*)&sS[i * 64 + j0] = *(const float4*)&carry[(size_t)bh * 4096 + gi * 64 + j0];

    float4 rA[4];
    {
        size_t cb0 = (size_t)bh * NC * 4096;
#pragma unroll
        for (int it = 0; it < 4; ++it)
            rA[it] = ((const float4*)(Ac + cb0))[it * 256 + t];
    }

    for (int c = 0; c < NC; ++c) {
        size_t cb = ((size_t)bh * NC + c) * 4096;
        __syncthreads();                 // prev iter's sA/sS consumers done
#pragma unroll
        for (int it = 0; it < 4; ++it)
            *(float4*)&sA[(it * 256 + t) * 4] = rA[it];
        if (c + 1 < NC) {
            size_t cbn = cb + 4096;
#pragma unroll
            for (int it = 0; it < 4; ++it)
                rA[it] = ((const float4*)(Ac + cbn))[it * 256 + t];
        }
        float4 acc = *(const float4*)&Bc[cb + (size_t)gi * 64 + j0];   // read Bc first
        float4 scur = *(float4*)&sS[i * 64 + j0];
        *(float4*)&S0[cb + (size_t)gi * 64 + j0] = scur;               // then write S0
        __syncthreads();                 // sA ready
#pragma unroll 4
        for (int p = 0; p < 64; ++p) {
            float stp = sS[i * 64 + p];
            float4 a4 = *(const float4*)&sA[p * 64 + j0];
            acc.x = fmaf(stp, a4.x, acc.x);
            acc.y = fmaf(stp, a4.y, acc.y);
            acc.z = fmaf(stp, a4.z, acc.z);
            acc.w = fmaf(stp, a4.w, acc.w);
        }
        __syncthreads();                 // all reads of sS done
        *(float4*)&sS[i * 64 + j0] = acc;
    }
    __syncthreads();
    *(float4*)&carry_out[(size_t)bh * 4096 + gi * 64 + j0] = *(float4*)&sS[i * 64 + j0];
}

// ------------------------------------------------------------------
// Phase 3: rerun recurrence from S0, emit x_s = St q_s into the q
// columns of proj. Lane-per-row, one wave per chunk, no shuffles.
// ------------------------------------------------------------------
__global__ __launch_bounds__(64) void k_emit_x(
    float* __restrict__ proj, const float* __restrict__ maskf,
    const float* __restrict__ S0)
{
    int c = blockIdx.x;
    int bh = blockIdx.y;
    int b = bh >> 3, h = bh & 7;
    int lane = threadIdx.x;
    __shared__ float sK[CL][128];
    __shared__ float sV[CL][128];
    __shared__ float sQ[CL][64];
    __shared__ float4 sScal[CL];

    size_t tokbase = (size_t)(b * S_ + c * CL);
#pragma unroll
    for (int it = 0; it < (CL * 32) / 64; ++it) {
        int f = it * 64 + lane;
        int tok = f >> 5, wi = f & 31;
        *(float4*)&sK[tok][wi * 4] = *(const float4*)&proj[(tokbase + tok) * NPROJ + KOFF + h * 128 + wi * 4];
        *(float4*)&sV[tok][wi * 4] = *(const float4*)&proj[(tokbase + tok) * NPROJ + VOFF + h * 128 + wi * 4];
    }
#pragma unroll
    for (int it = 0; it < (CL * 16) / 64; ++it) {
        int f = it * 64 + lane;
        int tok = f >> 4, wi = f & 15;
        *(float4*)&sQ[tok][wi * 4] = *(const float4*)&proj[(tokbase + tok) * NPROJ + QOFF + h * 64 + wi * 4];
    }
    if (lane < CL) {
        float r0 = proj[(tokbase + lane) * NPROJ + BOFF + h * 2 + 0];
        float r1 = proj[(tokbase + lane) * NPROJ + BOFF + h * 2 + 1];
        float ms = 1.f - maskf[tokbase + lane];
        sScal[lane] = make_float4(1.f / (1.f + expf(-r0)), 1.f / (1.f + expf(-r1)), ms, 0.f);
    }
    __syncthreads();

    float St[64];
    const float* sp = S0 + ((size_t)bh * NC + c) * 4096 + (size_t)lane * 64;
#pragma unroll
    for (int j = 0; j < 16; ++j) {
        float4 s4 = *(const float4*)&sp[j * 4];
        St[j * 4] = s4.x; St[j * 4 + 1] = s4.y; St[j * 4 + 2] = s4.z; St[j * 4 + 3] = s4.w;
    }

    for (int sl = 0; sl < CL; ++sl) {
        float4 sc = sScal[sl];
        if (sc.z == 0.f) {
#pragma unroll
            for (int j = 0; j < 64; ++j) St[j] = 0.f;
        }
#pragma unroll
        for (int r = 0; r < 2; ++r) {
            float br = (r == 0) ? sc.x : sc.y;
            float vi = sV[sl][r * 64 + lane];
            float4 kk[16];
#pragma unroll
            for (int j = 0; j < 16; ++j) kk[j] = *(const float4*)&sK[sl][r * 64 + j * 4];
            float u0 = 0.f, u1 = 0.f, u2 = 0.f, u3 = 0.f;
#pragma unroll
            for (int j = 0; j < 16; ++j) {
                u0 = fmaf(St[j * 4 + 0], kk[j].x, u0);
                u1 = fmaf(St[j * 4 + 1], kk[j].y, u1);
                u2 = fmaf(St[j * 4 + 2], kk[j].z, u2);
                u3 = fmaf(St[j * 4 + 3], kk[j].w, u3);
            }
            float u = (u0 + u1) + (u2 + u3);
            float coef = br * (vi - u);
#pragma unroll
            for (int j = 0; j < 16; ++j) {
                St[j * 4 + 0] = fmaf(coef, kk[j].x, St[j * 4 + 0]);
                St[j * 4 + 1] = fmaf(coef, kk[j].y, St[j * 4 + 1]);
                St[j * 4 + 2] = fmaf(coef, kk[j].z, St[j * 4 + 2]);
                St[j * 4 + 3] = fmaf(coef, kk[j].w, St[j * 4 + 3]);
            }
        }
        float x0 = 0.f, x1 = 0.f, x2 = 0.f, x3 = 0.f;
#pragma unroll
        for (int j = 0; j < 16; ++j) {
            float4 qq = *(const float4*)&sQ[sl][j * 4];
            x0 = fmaf(St[j * 4 + 0], qq.x, x0);
            x1 = fmaf(St[j * 4 + 1], qq.y, x1);
            x2 = fmaf(St[j * 4 + 2], qq.z, x2);
            x3 = fmaf(St[j * 4 + 3], qq.w, x3);
        }
        float xv = (x0 + x1) + (x2 + x3);
        proj[(tokbase + sl) * NPROJ + QOFF + h * 64 + lane] = xv;
    }
}

// ------------------------------------------------------------------
// RMS norm over x = proj cols 0..511, * rms_scale, emit compact bf16.
// ------------------------------------------------------------------
__global__ void k_rms_bf16(const float* __restrict__ proj, const float* __restrict__ scale,
                           unsigned short* __restrict__ xo) {
    int w = threadIdx.x >> 6;
    int l = threadIdx.x & 63;
    size_t row = (size_t)blockIdx.x * 4 + w;
    float4 v0 = *(const float4*)&proj[row * NPROJ + l * 8];
    float4 v1 = *(const float4*)&proj[row * NPROJ + l * 8 + 4];
    float ss = v0.x * v0.x + v0.y * v0.y + v0.z * v0.z + v0.w * v0.w
             + v1.x * v1.x + v1.y * v1.y + v1.z * v1.z + v1.w * v1.w;
#pragma unroll
    for (int m = 1; m < 64; m <<= 1) ss += __shfl_xor(ss, m);
    float sc = rsqrtf(ss * (1.f / 512.f) + 1e-6f);
    float4 s0 = *(const float4*)&scale[l * 8];
    float4 s1 = *(const float4*)&scale[l * 8 + 4];
    ushort8 o;
    o[0] = f2bf(v0.x * sc * s0.x); o[1] = f2bf(v0.y * sc * s0.y);
    o[2] = f2bf(v0.z * sc * s0.z); o[3] = f2bf(v0.w * sc * s0.w);
    o[4] = f2bf(v1.x * sc * s1.x); o[5] = f2bf(v1.y * sc * s1.y);
    o[6] = f2bf(v1.z * sc * s1.z); o[7] = f2bf(v1.w * sc * s1.w);
    *(ushort8*)&xo[row * 512 + l * 8] = o;
}

// ------------------------------------------------------------------
extern "C" void kernel_launch(void* const* d_in, const int* in_sizes, int n_in,
                              void* d_out, int out_size, void* d_ws, size_t ws_size,
                              hipStream_t stream) {
    const float* inputs    = (const float*)d_in[0];
    const void*  mask      = d_in[1];
    const float* carry     = (const float*)d_in[2];
    const float* Wq        = (const float*)d_in[3];
    const float* Wk        = (const float*)d_in[4];
    const float* Wv        = (const float*)d_in[5];
    const float* Wb        = (const float*)d_in[6];
    const float* rms_scale = (const float*)d_in[7];
    const float* Wo        = (const float*)d_in[8];
    const float* bo        = (const float*)d_in[9];

    float* out_carry = (float*)d_out;
    float* out_y     = (float*)d_out + (size_t)B_ * H_ * D_ * D_;

    const int M = B_ * S_;  // 2048
    float* ws = (float*)d_ws;
    size_t o = 0;
    float* proj = ws + o; o += (size_t)M * NPROJ;
    float* mf   = ws + o; o += (size_t)M;
    float* Ac   = ws + o; o += (size_t)BH * NC * 4096;
    float* Bc   = ws + o; o += (size_t)BH * NC * 4096;   // reused as S0
    unsigned short* inb = (unsigned short*)(ws + o); o += (size_t)M * 512;
    unsigned short* wt  = (unsigned short*)(ws + o); o += (size_t)NPROJ * 512;
    unsigned short* xbf = (unsigned short*)(ws + o); o += (size_t)M * 256;
    float* S0 = Bc;

    k_mask_prep<<<1, 256, 0, stream>>>(mask, mf, M);
    k_f32_to_bf16<<<(M * 1024) / 1024, 256, 0, stream>>>(inputs, inb, M * 1024);

    // pack W^T = [Wq^T | Wk^T | Wv^T | Wb^T(pad to 64)] as [NPROJ,1024] bf16
    k_transpose_to_bf16<<<dim3(512 / 32, 1024 / 32), 256, 0, stream>>>(Wq, wt + (size_t)QOFF * 1024, 1024, 512);
    k_transpose_to_bf16<<<dim3(1024 / 32, 1024 / 32), 256, 0, stream>>>(Wk, wt + (size_t)KOFF * 1024, 1024, 1024);
    k_transpose_to_bf16<<<dim3(1024 / 32, 1024 / 32), 256, 0, stream>>>(Wv, wt + (size_t)VOFF * 1024, 1024, 1024);
    k_wb_pad<<<64, 256, 0, stream>>>(Wb, wt + (size_t)BOFF * 1024);

    // proj = inputs @ [Wq|Wk|Wv|Wb]
    k_gemm_bf16<<<dim3(NPROJ / 64, M / 128), 256, 0, stream>>>(inb, wt, nullptr, proj, M, NPROJ, 1024);

    // silu+L2norm on q (8 groups/row) and k (16 groups/row)
    k_silu_norm<<<(M * 8) / 4, 256, 0, stream>>>(proj, M * 8, 3, 7, NPROJ, QOFF);
    k_silu_norm<<<(M * 16) / 4, 256, 0, stream>>>(proj, M * 16, 4, 15, NPROJ, KOFF);

    k_chunk_transfer<<<dim3(NC, BH), 128, 0, stream>>>(proj, mf, Ac, Bc);
    k_combine<<<BH * 4, 256, 0, stream>>>(Ac, Bc, carry, S0, out_carry);
    k_emit_x<<<dim3(NC, BH), 64, 0, stream>>>(proj, mf, S0);

    k_rms_bf16<<<M / 4, 256, 0, stream>>>(proj, rms_scale, xbf);

    // y = x @ Wo + bo  (K=512, N=1024); reuse wt for Wo^T
    k_transpose_to_bf16<<<dim3(1024 / 32, 512 / 32), 256, 0, stream>>>(Wo, wt, 512, 1024);
    k_gemm_bf16<<<dim3(1024 / 64, M / 128), 256, 0, stream>>>(xbf, wt, bo, out_y, M, 1024, 512);
}

// Round 6
// 212.628 us; speedup vs baseline: 1.1951x; 1.1951x over previous
//
#include <hip/hip_runtime.h>
#include <hip/hip_bf16.h>

#define B_ 2
#define S_ 1024
#define F_ 1024
#define H_ 8
#define D_ 64
#define R_ 2
#define BH (B_*H_)
#define NC 32
#define CL (S_/NC)   // 32

// combined projection layout: [M, NPROJ] fp32
#define QOFF 0
#define KOFF 512
#define VOFF 1536
#define BOFF 2560
#define NPROJ 2624   // 41 * 64

typedef __bf16 bf16x8 __attribute__((ext_vector_type(8)));
typedef unsigned short ushort8 __attribute__((ext_vector_type(8)));
typedef float f32x4 __attribute__((ext_vector_type(4)));

__device__ __forceinline__ unsigned short f2bf(float f) {
    unsigned u = __builtin_bit_cast(unsigned, f);
    unsigned r = u + 0x7FFFu + ((u >> 16) & 1u);
    return (unsigned short)(r >> 16);
}

__device__ __forceinline__ void gload_lds16(const void* g, void* l) {
    __builtin_amdgcn_global_load_lds(
        (const __attribute__((address_space(1))) void*)g,
        (__attribute__((address_space(3))) void*)l, 16, 0, 0);
}

// ------------------------------------------------------------------
// Mask format sniffer + normalize to float 0/1.
// ------------------------------------------------------------------
__global__ void k_mask_prep(const void* __restrict__ mraw, float* __restrict__ maskf, int n) {
    __shared__ int fmt; // 0=int32, 1=byte, 2=float32
    int t = threadIdx.x;
    if (t == 0) fmt = 0;
    __syncthreads();
    const unsigned int* u32 = (const unsigned int*)mraw;
    for (int g = t; g < n / 4; g += blockDim.x) {
        unsigned int v = u32[g];
        if (v == 0x3F800000u) atomicMax(&fmt, 2);
        else if (v != 0u && v != 1u) atomicMax(&fmt, 1);
    }
    __syncthreads();
    int f = fmt;
    const unsigned char* u8 = (const unsigned char*)mraw;
    const float* f32 = (const float*)mraw;
    for (int i = t; i < n; i += blockDim.x) {
        float mv;
        if (f == 1)      mv = u8[i] ? 1.f : 0.f;
        else if (f == 2) mv = (f32[i] != 0.f) ? 1.f : 0.f;
        else             mv = (u32[i] != 0u) ? 1.f : 0.f;
        maskf[i] = mv;
    }
}

// ------------------------------------------------------------------
// fp32 -> bf16 elementwise (n % 4 == 0)
// ------------------------------------------------------------------
__global__ void k_f32_to_bf16(const float* __restrict__ s, unsigned short* __restrict__ d, int n) {
    int i = (blockIdx.x * blockDim.x + threadIdx.x) * 4;
    if (i < n) {
        float4 v = *(const float4*)&s[i];
        d[i + 0] = f2bf(v.x); d[i + 1] = f2bf(v.y);
        d[i + 2] = f2bf(v.z); d[i + 3] = f2bf(v.w);
    }
}

// ------------------------------------------------------------------
// Transpose [K,N] f32 -> [N,K] bf16. 32x32 tiles, 256 threads.
// ------------------------------------------------------------------
__global__ __launch_bounds__(256) void k_transpose_to_bf16(
    const float* __restrict__ src, unsigned short* __restrict__ dst, int K, int N)
{
    __shared__ float tile[32][33];
    int bx = blockIdx.x, by = blockIdx.y;
    int tx = threadIdx.x & 31, ty = threadIdx.x >> 5;
#pragma unroll
    for (int i = 0; i < 32; i += 8)
        tile[ty + i][tx] = src[(size_t)(by * 32 + ty + i) * N + bx * 32 + tx];
    __syncthreads();
#pragma unroll
    for (int i = 0; i < 32; i += 8)
        dst[(size_t)(bx * 32 + ty + i) * K + by * 32 + tx] = f2bf(tile[tx][ty + i]);
}

// ------------------------------------------------------------------
// Wb [1024,16] f32 -> rows BOFF..BOFF+63 of wt as [64,1024] bf16.
// ------------------------------------------------------------------
__global__ void k_wb_pad(const float* __restrict__ Wb, unsigned short* __restrict__ dst) {
    int row = blockIdx.x;
    int c0 = threadIdx.x * 4;
#pragma unroll
    for (int c = c0; c < c0 + 4; ++c)
        dst[(size_t)row * 1024 + c] = (row < 16) ? f2bf(Wb[(size_t)c * 16 + row]) : (unsigned short)0;
}

// ------------------------------------------------------------------
// bf16 MFMA GEMM: C[M,N] = A[M,K] @ B[K,N] (+bias). Tile 128x64, BK=64.
// ------------------------------------------------------------------
__global__ __launch_bounds__(256) void k_gemm_bf16(
    const unsigned short* __restrict__ A, const unsigned short* __restrict__ Bt,
    const float* __restrict__ bias, float* __restrict__ C,
    int M, int N, int K)
{
    constexpr int BM = 128, BN = 64, BK = 64;
    __shared__ unsigned short sA[BM * BK];
    __shared__ unsigned short sB[BN * BK];
    int t = threadIdx.x;
    int w = t >> 6, l = t & 63;
    int rowb = blockIdx.y * BM, colb = blockIdx.x * BN;
    int wr = w >> 1, wc = w & 1;
    int fr = l & 15, kgrp = l >> 4;

    f32x4 acc[4][2];
#pragma unroll
    for (int m = 0; m < 4; ++m)
#pragma unroll
        for (int n = 0; n < 2; ++n) acc[m][n] = (f32x4){0.f, 0.f, 0.f, 0.f};

    int lrow_off = l >> 3;
    int kg_phys = l & 7;

    for (int k0 = 0; k0 < K; k0 += BK) {
        __syncthreads();
#pragma unroll
        for (int is = 0; is < 4; ++is) {
            int r0 = (w * 4 + is) * 8;
            int row = r0 + lrow_off;
            int kg_log = kg_phys ^ (row & 7);
            gload_lds16(A + (size_t)(rowb + row) * K + k0 + kg_log * 8, &sA[r0 * BK]);
        }
#pragma unroll
        for (int is = 0; is < 2; ++is) {
            int r0 = (w * 2 + is) * 8;
            int row = r0 + lrow_off;
            int kg_log = kg_phys ^ (row & 7);
            gload_lds16(Bt + (size_t)(colb + row) * K + k0 + kg_log * 8, &sB[r0 * BK]);
        }
        asm volatile("s_waitcnt vmcnt(0)" ::: "memory");
        __syncthreads();

#pragma unroll
        for (int kk = 0; kk < BK; kk += 32) {
            int kg = (kk >> 3) + kgrp;
            bf16x8 af[4], bfv[2];
#pragma unroll
            for (int m = 0; m < 4; ++m) {
                int row = wr * 64 + m * 16 + fr;
                ushort8 raw = *(const ushort8*)&sA[row * BK + (kg ^ (row & 7)) * 8];
                af[m] = __builtin_bit_cast(bf16x8, raw);
            }
#pragma unroll
            for (int n = 0; n < 2; ++n) {
                int row = wc * 32 + n * 16 + fr;
                ushort8 raw = *(const ushort8*)&sB[row * BK + (kg ^ (row & 7)) * 8];
                bfv[n] = __builtin_bit_cast(bf16x8, raw);
            }
#pragma unroll
            for (int m = 0; m < 4; ++m)
#pragma unroll
                for (int n = 0; n < 2; ++n)
                    acc[m][n] = __builtin_amdgcn_mfma_f32_16x16x32_bf16(af[m], bfv[n], acc[m][n], 0, 0, 0);
        }
    }

#pragma unroll
    for (int m = 0; m < 4; ++m)
#pragma unroll
        for (int n = 0; n < 2; ++n) {
            int grow0 = rowb + wr * 64 + m * 16 + kgrp * 4;
            int gcol  = colb + wc * 32 + n * 16 + fr;
            float bv = bias ? bias[gcol] : 0.f;
#pragma unroll
            for (int r = 0; r < 4; ++r)
                C[(size_t)(grow0 + r) * N + gcol] = acc[m][n][r] + bv;
        }
}

// ------------------------------------------------------------------
// silu then L2-normalize per group of 64 with strided row layout.
// ------------------------------------------------------------------
__global__ void k_silu_norm(float* __restrict__ buf, int ngroups,
                            int gshift, int gmask, int rowstride, int coloff) {
    int w = threadIdx.x >> 6;
    int l = threadIdx.x & 63;
    int g = blockIdx.x * 4 + w;
    if (g >= ngroups) return;
    size_t idx = (size_t)(g >> gshift) * rowstride + coloff + ((g & gmask) << 6) + l;
    float x = buf[idx];
    float s = x / (1.f + expf(-x));
    float ss = s * s;
#pragma unroll
    for (int m = 1; m < 64; m <<= 1) ss += __shfl_xor(ss, m);
    float nrm = sqrtf(ss) + 1e-6f;
    buf[idx] = s / nrm;
}

// ------------------------------------------------------------------
// Phase 1: per (bh, chunk) transfer operators (A_c, B_c).
// Lane-per-row; wave 0 = A-state, wave 1 = B-state. K staged to LDS
// via global_load_lds; V read direct from global, prefetched 1 token
// ahead (each V element consumed once by one lane).
// ------------------------------------------------------------------
__global__ __launch_bounds__(128) void k_chunk_transfer(
    const float* __restrict__ proj, const float* __restrict__ maskf,
    float* __restrict__ Ac, float* __restrict__ Bc)
{
    int c = blockIdx.x;
    int bh = blockIdx.y;
    int b = bh >> 3, h = bh & 7;
    int t = threadIdx.x;
    int w = t >> 6, lane = t & 63;
    __shared__ float sK[CL][128];   // 16 KB
    __shared__ float4 sScal[CL];

    size_t tokbase = (size_t)(b * S_ + c * CL);
    // stage K: CL*32 float4 = 1024 issues of 16B; 8 per thread
#pragma unroll
    for (int it = 0; it < (CL * 32) / 128; ++it) {
        int f = it * 128 + t;
        int tok = f >> 5, wi = f & 31;
        gload_lds16(&proj[(tokbase + tok) * NPROJ + KOFF + h * 128 + wi * 4],
                    &sK[0][0] + (size_t)(it * 128 + w * 64) * 4);
    }
    if (t < CL) {
        float r0 = proj[(tokbase + t) * NPROJ + BOFF + h * 2 + 0];
        float r1 = proj[(tokbase + t) * NPROJ + BOFF + h * 2 + 1];
        float ms = 1.f - maskf[tokbase + t];
        sScal[t] = make_float4(1.f / (1.f + expf(-r0)), 1.f / (1.f + expf(-r1)), ms, 0.f);
    }
    asm volatile("s_waitcnt vmcnt(0)" ::: "memory");
    __syncthreads();

    float St[64];
#pragma unroll
    for (int j = 0; j < 64; ++j) St[j] = (w == 0 && j == lane) ? 1.f : 0.f;

    const float* vbase = &proj[tokbase * NPROJ + VOFF + h * 128];
    float v0 = vbase[lane], v1 = vbase[64 + lane];

    for (int sl = 0; sl < CL; ++sl) {
        float vc0 = v0, vc1 = v1;
        if (sl + 1 < CL) {
            const float* nb = vbase + (size_t)(sl + 1) * NPROJ;
            v0 = nb[lane]; v1 = nb[64 + lane];
        }
        float4 sc = sScal[sl];
        if (sc.z == 0.f) {           // masked token (rare, wave-uniform)
#pragma unroll
            for (int j = 0; j < 64; ++j) St[j] = 0.f;
        }
#pragma unroll
        for (int r = 0; r < 2; ++r) {
            float br = (r == 0) ? sc.x : sc.y;
            float vi = (r == 0) ? vc0 : vc1;
            float4 kk[16];
#pragma unroll
            for (int j = 0; j < 16; ++j) kk[j] = *(const float4*)&sK[sl][r * 64 + j * 4];
            float u0 = 0.f, u1 = 0.f, u2 = 0.f, u3 = 0.f;
#pragma unroll
            for (int j = 0; j < 16; ++j) {
                u0 = fmaf(St[j * 4 + 0], kk[j].x, u0);
                u1 = fmaf(St[j * 4 + 1], kk[j].y, u1);
                u2 = fmaf(St[j * 4 + 2], kk[j].z, u2);
                u3 = fmaf(St[j * 4 + 3], kk[j].w, u3);
            }
            float u = (u0 + u1) + (u2 + u3);
            float coef = (w == 0) ? (-br * u) : (br * (vi - u));
#pragma unroll
            for (int j = 0; j < 16; ++j) {
                St[j * 4 + 0] = fmaf(coef, kk[j].x, St[j * 4 + 0]);
                St[j * 4 + 1] = fmaf(coef, kk[j].y, St[j * 4 + 1]);
                St[j * 4 + 2] = fmaf(coef, kk[j].z, St[j * 4 + 2]);
                St[j * 4 + 3] = fmaf(coef, kk[j].w, St[j * 4 + 3]);
            }
        }
    }
    float* dst = (w == 0 ? Ac : Bc) + ((size_t)bh * NC + c) * 4096 + (size_t)lane * 64;
#pragma unroll
    for (int j = 0; j < 16; ++j)
        *(float4*)&dst[j * 4] = make_float4(St[j * 4], St[j * 4 + 1], St[j * 4 + 2], St[j * 4 + 3]);
}

// ------------------------------------------------------------------
// Phase 2: sequential chunk combine, 64 blocks = 16 bh x 4 row-groups
// of 16 rows. Async LDS double-buffer for A; Bc register-prefetched
// one step ahead; padded state rows (stride 68) kill bank conflicts;
// S0 separate buffer (no alias), written from registers.
// ------------------------------------------------------------------
__global__ __launch_bounds__(256) void k_combine(
    const float* __restrict__ Ac, const float* __restrict__ Bc,
    const float* __restrict__ carry, float* __restrict__ S0,
    float* __restrict__ carry_out)
{
    constexpr int SP = 68;
    int blk = blockIdx.x;
    int bh = blk >> 2, rg = blk & 3;
    int t = threadIdx.x;
    int i = t >> 4;              // local row 0..15
    int j0 = (t & 15) * 4;       // col
    int gi = rg * 16 + i;        // global row
    __shared__ float sA[2][64 * 64];   // 32 KB
    __shared__ float sS[16 * SP];      // padded state rows

    size_t cb0 = (size_t)bh * NC * 4096;
    // prologue: stage A[0], prefetch B[0], init state
#pragma unroll
    for (int s = 0; s < 4; ++s)
        gload_lds16(Ac + cb0 + (size_t)(s * 256 + t) * 4, &sA[0][(size_t)(s * 256 + (t & 192)) * 4]);
    float4 rB = *(const float4*)&Bc[cb0 + (size_t)gi * 64 + j0];
    float4 racc = *(const float4*)&carry[(size_t)bh * 4096 + (size_t)gi * 64 + j0];
    *(float4*)&sS[i * SP + j0] = racc;
    asm volatile("s_waitcnt vmcnt(0)" ::: "memory");
    __syncthreads();

    for (int c = 0; c < NC; ++c) {
        int cur = c & 1;
        size_t cb = cb0 + (size_t)c * 4096;
        float4 rBn;
        if (c + 1 < NC) {
#pragma unroll
            for (int s = 0; s < 4; ++s)
                gload_lds16(Ac + cb + 4096 + (size_t)(s * 256 + t) * 4,
                            &sA[cur ^ 1][(size_t)(s * 256 + (t & 192)) * 4]);
            rBn = *(const float4*)&Bc[cb + 4096 + (size_t)gi * 64 + j0];
        }
        *(float4*)&S0[cb + (size_t)gi * 64 + j0] = racc;   // state before chunk c
        float4 acc = rB;
        float4 ac2 = make_float4(0.f, 0.f, 0.f, 0.f);
#pragma unroll
        for (int p4 = 0; p4 < 16; p4 += 2) {
            float4 s0v = *(const float4*)&sS[i * SP + p4 * 4];
            float4 s1v = *(const float4*)&sS[i * SP + p4 * 4 + 4];
            float4 a0 = *(const float4*)&sA[cur][(p4 * 4 + 0) * 64 + j0];
            float4 a1 = *(const float4*)&sA[cur][(p4 * 4 + 1) * 64 + j0];
            float4 a2 = *(const float4*)&sA[cur][(p4 * 4 + 2) * 64 + j0];
            float4 a3 = *(const float4*)&sA[cur][(p4 * 4 + 3) * 64 + j0];
            float4 a4 = *(const float4*)&sA[cur][(p4 * 4 + 4) * 64 + j0];
            float4 a5 = *(const float4*)&sA[cur][(p4 * 4 + 5) * 64 + j0];
            float4 a6 = *(const float4*)&sA[cur][(p4 * 4 + 6) * 64 + j0];
            float4 a7 = *(const float4*)&sA[cur][(p4 * 4 + 7) * 64 + j0];
            acc.x = fmaf(s0v.x, a0.x, acc.x); acc.y = fmaf(s0v.x, a0.y, acc.y);
            acc.z = fmaf(s0v.x, a0.z, acc.z); acc.w = fmaf(s0v.x, a0.w, acc.w);
            ac2.x = fmaf(s0v.y, a1.x, ac2.x); ac2.y = fmaf(s0v.y, a1.y, ac2.y);
            ac2.z = fmaf(s0v.y, a1.z, ac2.z); ac2.w = fmaf(s0v.y, a1.w, ac2.w);
            acc.x = fmaf(s0v.z, a2.x, acc.x); acc.y = fmaf(s0v.z, a2.y, acc.y);
            acc.z = fmaf(s0v.z, a2.z, acc.z); acc.w = fmaf(s0v.z, a2.w, acc.w);
            ac2.x = fmaf(s0v.w, a3.x, ac2.x); ac2.y = fmaf(s0v.w, a3.y, ac2.y);
            ac2.z = fmaf(s0v.w, a3.z, ac2.z); ac2.w = fmaf(s0v.w, a3.w, ac2.w);
            acc.x = fmaf(s1v.x, a4.x, acc.x); acc.y = fmaf(s1v.x, a4.y, acc.y);
            acc.z = fmaf(s1v.x, a4.z, acc.z); acc.w = fmaf(s1v.x, a4.w, acc.w);
            ac2.x = fmaf(s1v.y, a5.x, ac2.x); ac2.y = fmaf(s1v.y, a5.y, ac2.y);
            ac2.z = fmaf(s1v.y, a5.z, ac2.z); ac2.w = fmaf(s1v.y, a5.w, ac2.w);
            acc.x = fmaf(s1v.z, a6.x, acc.x); acc.y = fmaf(s1v.z, a6.y, acc.y);
            acc.z = fmaf(s1v.z, a6.z, acc.z); acc.w = fmaf(s1v.z, a6.w, acc.w);
            ac2.x = fmaf(s1v.w, a7.x, ac2.x); ac2.y = fmaf(s1v.w, a7.y, ac2.y);
            ac2.z = fmaf(s1v.w, a7.z, ac2.z); ac2.w = fmaf(s1v.w, a7.w, ac2.w);
        }
        acc.x += ac2.x; acc.y += ac2.y; acc.z += ac2.z; acc.w += ac2.w;
        __syncthreads();                       // all reads of sS done
        *(float4*)&sS[i * SP + j0] = acc;
        racc = acc;
        rB = rBn;
        asm volatile("s_waitcnt vmcnt(0)" ::: "memory");   // next A staged
        __syncthreads();                       // sS update visible
    }
    *(float4*)&carry_out[(size_t)bh * 4096 + (size_t)gi * 64 + j0] = racc;
}

// ------------------------------------------------------------------
// Phase 3: rerun recurrence from S0, emit x_s = St q_s into the q
// columns of proj. Lane-per-row, 1 wave; K/Q staged via
// global_load_lds; V direct-prefetched.
// ------------------------------------------------------------------
__global__ __launch_bounds__(64) void k_emit_x(
    float* __restrict__ proj, const float* __restrict__ maskf,
    const float* __restrict__ S0)
{
    int c = blockIdx.x;
    int bh = blockIdx.y;
    int b = bh >> 3, h = bh & 7;
    int lane = threadIdx.x;
    __shared__ float sK[CL][128];   // 16 KB
    __shared__ float sQ[CL][64];    // 8 KB
    __shared__ float4 sScal[CL];

    size_t tokbase = (size_t)(b * S_ + c * CL);
#pragma unroll
    for (int it = 0; it < (CL * 32) / 64; ++it) {
        int f = it * 64 + lane;
        int tok = f >> 5, wi = f & 31;
        gload_lds16(&proj[(tokbase + tok) * NPROJ + KOFF + h * 128 + wi * 4],
                    &sK[0][0] + (size_t)(it * 64) * 4);
    }
#pragma unroll
    for (int it = 0; it < (CL * 16) / 64; ++it) {
        int f = it * 64 + lane;
        int tok = f >> 4, wi = f & 15;
        gload_lds16(&proj[(tokbase + tok) * NPROJ + QOFF + h * 64 + wi * 4],
                    &sQ[0][0] + (size_t)(it * 64) * 4);
    }
    if (lane < CL) {
        float r0 = proj[(tokbase + lane) * NPROJ + BOFF + h * 2 + 0];
        float r1 = proj[(tokbase + lane) * NPROJ + BOFF + h * 2 + 1];
        float ms = 1.f - maskf[tokbase + lane];
        sScal[lane] = make_float4(1.f / (1.f + expf(-r0)), 1.f / (1.f + expf(-r1)), ms, 0.f);
    }
    asm volatile("s_waitcnt vmcnt(0)" ::: "memory");
    __syncthreads();

    float St[64];
    const float* sp = S0 + ((size_t)bh * NC + c) * 4096 + (size_t)lane * 64;
#pragma unroll
    for (int j = 0; j < 16; ++j) {
        float4 s4 = *(const float4*)&sp[j * 4];
        St[j * 4] = s4.x; St[j * 4 + 1] = s4.y; St[j * 4 + 2] = s4.z; St[j * 4 + 3] = s4.w;
    }

    const float* vbase = &proj[tokbase * NPROJ + VOFF + h * 128];
    float v0 = vbase[lane], v1 = vbase[64 + lane];

    for (int sl = 0; sl < CL; ++sl) {
        float vc0 = v0, vc1 = v1;
        if (sl + 1 < CL) {
            const float* nb = vbase + (size_t)(sl + 1) * NPROJ;
            v0 = nb[lane]; v1 = nb[64 + lane];
        }
        float4 sc = sScal[sl];
        if (sc.z == 0.f) {
#pragma unroll
            for (int j = 0; j < 64; ++j) St[j] = 0.f;
        }
#pragma unroll
        for (int r = 0; r < 2; ++r) {
            float br = (r == 0) ? sc.x : sc.y;
            float vi = (r == 0) ? vc0 : vc1;
            float4 kk[16];
#pragma unroll
            for (int j = 0; j < 16; ++j) kk[j] = *(const float4*)&sK[sl][r * 64 + j * 4];
            float u0 = 0.f, u1 = 0.f, u2 = 0.f, u3 = 0.f;
#pragma unroll
            for (int j = 0; j < 16; ++j) {
                u0 = fmaf(St[j * 4 + 0], kk[j].x, u0);
                u1 = fmaf(St[j * 4 + 1], kk[j].y, u1);
                u2 = fmaf(St[j * 4 + 2], kk[j].z, u2);
                u3 = fmaf(St[j * 4 + 3], kk[j].w, u3);
            }
            float u = (u0 + u1) + (u2 + u3);
            float coef = br * (vi - u);
#pragma unroll
            for (int j = 0; j < 16; ++j) {
                St[j * 4 + 0] = fmaf(coef, kk[j].x, St[j * 4 + 0]);
                St[j * 4 + 1] = fmaf(coef, kk[j].y, St[j * 4 + 1]);
                St[j * 4 + 2] = fmaf(coef, kk[j].z, St[j * 4 + 2]);
                St[j * 4 + 3] = fmaf(coef, kk[j].w, St[j * 4 + 3]);
            }
        }
        float x0 = 0.f, x1 = 0.f, x2 = 0.f, x3 = 0.f;
#pragma unroll
        for (int j = 0; j < 16; ++j) {
            float4 qq = *(const float4*)&sQ[sl][j * 4];
            x0 = fmaf(St[j * 4 + 0], qq.x, x0);
            x1 = fmaf(St[j * 4 + 1], qq.y, x1);
            x2 = fmaf(St[j * 4 + 2], qq.z, x2);
            x3 = fmaf(St[j * 4 + 3], qq.w, x3);
        }
        float xv = (x0 + x1) + (x2 + x3);
        proj[(tokbase + sl) * NPROJ + QOFF + h * 64 + lane] = xv;
    }
}

// ------------------------------------------------------------------
// RMS norm over x = proj cols 0..511, * rms_scale, emit compact bf16.
// ------------------------------------------------------------------
__global__ void k_rms_bf16(const float* __restrict__ proj, const float* __restrict__ scale,
                           unsigned short* __restrict__ xo) {
    int w = threadIdx.x >> 6;
    int l = threadIdx.x & 63;
    size_t row = (size_t)blockIdx.x * 4 + w;
    float4 v0 = *(const float4*)&proj[row * NPROJ + l * 8];
    float4 v1 = *(const float4*)&proj[row * NPROJ + l * 8 + 4];
    float ss = v0.x * v0.x + v0.y * v0.y + v0.z * v0.z + v0.w * v0.w
             + v1.x * v1.x + v1.y * v1.y + v1.z * v1.z + v1.w * v1.w;
#pragma unroll
    for (int m = 1; m < 64; m <<= 1) ss += __shfl_xor(ss, m);
    float sc = rsqrtf(ss * (1.f / 512.f) + 1e-6f);
    float4 s0 = *(const float4*)&scale[l * 8];
    float4 s1 = *(const float4*)&scale[l * 8 + 4];
    ushort8 o;
    o[0] = f2bf(v0.x * sc * s0.x); o[1] = f2bf(v0.y * sc * s0.y);
    o[2] = f2bf(v0.z * sc * s0.z); o[3] = f2bf(v0.w * sc * s0.w);
    o[4] = f2bf(v1.x * sc * s1.x); o[5] = f2bf(v1.y * sc * s1.y);
    o[6] = f2bf(v1.z * sc * s1.z); o[7] = f2bf(v1.w * sc * s1.w);
    *(ushort8*)&xo[row * 512 + l * 8] = o;
}

// ------------------------------------------------------------------
extern "C" void kernel_launch(void* const* d_in, const int* in_sizes, int n_in,
                              void* d_out, int out_size, void* d_ws, size_t ws_size,
                              hipStream_t stream) {
    const float* inputs    = (const float*)d_in[0];
    const void*  mask      = d_in[1];
    const float* carry     = (const float*)d_in[2];
    const float* Wq        = (const float*)d_in[3];
    const float* Wk        = (const float*)d_in[4];
    const float* Wv        = (const float*)d_in[5];
    const float* Wb        = (const float*)d_in[6];
    const float* rms_scale = (const float*)d_in[7];
    const float* Wo        = (const float*)d_in[8];
    const float* bo        = (const float*)d_in[9];

    float* out_carry = (float*)d_out;
    float* out_y     = (float*)d_out + (size_t)B_ * H_ * D_ * D_;

    const int M = B_ * S_;  // 2048
    float* ws = (float*)d_ws;
    size_t o = 0;
    float* proj = ws + o; o += (size_t)M * NPROJ;
    float* mf   = ws + o; o += (size_t)M;
    float* Ac   = ws + o; o += (size_t)BH * NC * 4096;
    float* Bc   = ws + o; o += (size_t)BH * NC * 4096;
    float* S0   = ws + o; o += (size_t)BH * NC * 4096;
    unsigned short* inb = (unsigned short*)(ws + o); o += (size_t)M * 512;
    unsigned short* wt  = (unsigned short*)(ws + o); o += (size_t)NPROJ * 512;
    unsigned short* xbf = (unsigned short*)(ws + o); o += (size_t)M * 256;

    k_mask_prep<<<1, 256, 0, stream>>>(mask, mf, M);
    k_f32_to_bf16<<<(M * 1024) / 1024, 256, 0, stream>>>(inputs, inb, M * 1024);

    // pack W^T = [Wq^T | Wk^T | Wv^T | Wb^T(pad to 64)] as [NPROJ,1024] bf16
    k_transpose_to_bf16<<<dim3(512 / 32, 1024 / 32), 256, 0, stream>>>(Wq, wt + (size_t)QOFF * 1024, 1024, 512);
    k_transpose_to_bf16<<<dim3(1024 / 32, 1024 / 32), 256, 0, stream>>>(Wk, wt + (size_t)KOFF * 1024, 1024, 1024);
    k_transpose_to_bf16<<<dim3(1024 / 32, 1024 / 32), 256, 0, stream>>>(Wv, wt + (size_t)VOFF * 1024, 1024, 1024);
    k_wb_pad<<<64, 256, 0, stream>>>(Wb, wt + (size_t)BOFF * 1024);

    // proj = inputs @ [Wq|Wk|Wv|Wb]
    k_gemm_bf16<<<dim3(NPROJ / 64, M / 128), 256, 0, stream>>>(inb, wt, nullptr, proj, M, NPROJ, 1024);

    // silu+L2norm on q (8 groups/row) and k (16 groups/row)
    k_silu_norm<<<(M * 8) / 4, 256, 0, stream>>>(proj, M * 8, 3, 7, NPROJ, QOFF);
    k_silu_norm<<<(M * 16) / 4, 256, 0, stream>>>(proj, M * 16, 4, 15, NPROJ, KOFF);

    k_chunk_transfer<<<dim3(NC, BH), 128, 0, stream>>>(proj, mf, Ac, Bc);
    k_combine<<<BH * 4, 256, 0, stream>>>(Ac, Bc, carry, S0, out_carry);
    k_emit_x<<<dim3(NC, BH), 64, 0, stream>>>(proj, mf, S0);

    k_rms_bf16<<<M / 4, 256, 0, stream>>>(proj, rms_scale, xbf);

    // y = x @ Wo + bo  (K=512, N=1024); reuse wt for Wo^T
    k_transpose_to_bf16<<<dim3(1024 / 32, 512 / 32), 256, 0, stream>>>(Wo, wt, 512, 1024);
    k_gemm_bf16<<<dim3(1024 / 64, M / 128), 256, 0, stream>>>(xbf, wt, bo, out_y, M, 1024, 512);
}